// Round 2
// baseline (494.657 us; speedup 1.0000x reference)
//
#include <hip/hip_runtime.h>

// NaiveCollider via uniform-grid broad phase with exact jnp.nonzero
// ordered-compaction semantics (row-major pair order, 4N broad / N narrow caps).

constexpr int NB = 8192;
constexpr int MAXB = 32768;               // = 4*NB, broad candidate cap
constexpr int GRID_DIM = 56;              // cell size 2.0 >= max rsum, 112/2
constexpr int NCELLS = GRID_DIM * GRID_DIM;
constexpr float INV_CELL = 0.5f;
constexpr float EPS = 1e-12f;

// workspace layout (int offsets; base is 256B-aligned so offset 0 is 8B-aligned)
constexpr int O_HITBITS = 0;                       // 512 uint64 = 1024 ints
constexpr int O_WSTART  = 1024;                    // 512 ints (exclusive word starts)
constexpr int O_CCOUNT  = 1536;                    // 3136
constexpr int O_CFILL   = O_CCOUNT + NCELLS;       // 3136
constexpr int O_CSTART  = O_CFILL + NCELLS;        // 3137
constexpr int O_SIDX    = O_CSTART + NCELLS + 1;   // 8192
constexpr int O_SX      = O_SIDX + NB;             // 8192 floats
constexpr int O_SY      = O_SX + NB;
constexpr int O_SR      = O_SY + NB;
constexpr int O_RCOUNT  = O_SR + NB;               // 8192
constexpr int O_RSTART  = O_RCOUNT + NB;           // 8193
constexpr int O_CAND    = O_RSTART + NB + 1;       // 32768
// total ~93k ints ~ 372 KB

__device__ __forceinline__ int cell_of(float v) {
    int c = (int)(v * INV_CELL);
    return c > GRID_DIM - 1 ? GRID_DIM - 1 : (c < 0 ? 0 : c);
}

__global__ void cell_count_kernel(const float2* __restrict__ centers,
                                  int* __restrict__ ccount) {
    int t = blockIdx.x * blockDim.x + threadIdx.x;
    if (t >= NB) return;
    float2 c = centers[t];
    atomicAdd(&ccount[cell_of(c.y) * GRID_DIM + cell_of(c.x)], 1);
}

template <int TPB, int IPT>
__global__ __launch_bounds__(TPB) void scan_kernel(const int* __restrict__ in,
                                                   int* __restrict__ out, int n) {
    __shared__ int bs[TPB];
    const int t = threadIdx.x;
    int v[IPT];
    int local = 0;
    const int base = t * IPT;
#pragma unroll
    for (int k = 0; k < IPT; ++k) {
        int idx = base + k;
        v[k] = (idx < n) ? in[idx] : 0;
        local += v[k];
    }
    bs[t] = local;
    __syncthreads();
    for (int off = 1; off < TPB; off <<= 1) {
        int add = (t >= off) ? bs[t - off] : 0;
        __syncthreads();
        if (t >= off) bs[t] += add;
        __syncthreads();
    }
    int run = (t == 0) ? 0 : bs[t - 1];
#pragma unroll
    for (int k = 0; k < IPT; ++k) {
        int idx = base + k;
        if (idx < n) out[idx] = run;
        run += v[k];
    }
    if (t == TPB - 1) out[n] = bs[TPB - 1];
}

__global__ void scatter_kernel(const float2* __restrict__ centers,
                               const float* __restrict__ radii,
                               const int* __restrict__ cstart, int* __restrict__ cfill,
                               int* __restrict__ sidx, float* __restrict__ sx,
                               float* __restrict__ sy, float* __restrict__ sr) {
    int t = blockIdx.x * blockDim.x + threadIdx.x;
    if (t >= NB) return;
    float2 c = centers[t];
    int cell = cell_of(c.y) * GRID_DIM + cell_of(c.x);
    int s = cstart[cell] + atomicAdd(&cfill[cell], 1);
    sidx[s] = t;
    sx[s] = c.x;
    sy[s] = c.y;
    sr[s] = radii[t];
}

__global__ void broad_count_kernel(const int* __restrict__ cstart,
                                   const int* __restrict__ sidx,
                                   const float* __restrict__ sx,
                                   const float* __restrict__ sy,
                                   const float* __restrict__ sr,
                                   int* __restrict__ rcount) {
    int t = blockIdx.x * blockDim.x + threadIdx.x;
    if (t >= NB) return;
    const int i = sidx[t];
    const float xi = sx[t], yi = sy[t], ri = sr[t];
    const int cx = cell_of(xi), cy = cell_of(yi);
    int cnt = 0;
    for (int yy = max(cy - 1, 0); yy <= min(cy + 1, GRID_DIM - 1); ++yy)
        for (int xx = max(cx - 1, 0); xx <= min(cx + 1, GRID_DIM - 1); ++xx) {
            const int c = yy * GRID_DIM + xx;
            const int e = cstart[c + 1];
            for (int s = cstart[c]; s < e; ++s) {
                int j = sidx[s];
                if (j <= i) continue;
                float rs = ri + sr[s];
                if (fabsf(xi - sx[s]) <= rs && fabsf(yi - sy[s]) <= rs) ++cnt;
            }
        }
    rcount[i] = cnt;
}

__global__ void emit_kernel(const int* __restrict__ cstart,
                            const int* __restrict__ sidx,
                            const float* __restrict__ sx,
                            const float* __restrict__ sy,
                            const float* __restrict__ sr,
                            const int* __restrict__ rstart,
                            const int* __restrict__ LBp,
                            int* __restrict__ cand) {
    int t = blockIdx.x * blockDim.x + threadIdx.x;
    if (t >= NB) return;
    const int i = sidx[t];
    const int g0 = rstart[i];
    const int LB = *LBp;
    if (g0 >= LB) return;  // every candidate in this row has global index >= LB
    const float xi = sx[t], yi = sy[t], ri = sr[t];
    const int cx = cell_of(xi), cy = cell_of(yi);
    const int y0 = max(cy - 1, 0), y1 = min(cy + 1, GRID_DIM - 1);
    const int x0 = max(cx - 1, 0), x1 = min(cx + 1, GRID_DIM - 1);
    for (int yy = y0; yy <= y1; ++yy)
        for (int xx = x0; xx <= x1; ++xx) {
            const int c = yy * GRID_DIM + xx;
            const int e = cstart[c + 1];
            for (int s = cstart[c]; s < e; ++s) {
                int j = sidx[s];
                if (j <= i) continue;
                float rs = ri + sr[s];
                if (!(fabsf(xi - sx[s]) <= rs && fabsf(yi - sy[s]) <= rs)) continue;
                // rank = #overlapping j' with i < j' < j (row-major nonzero order)
                int rank = 0;
                for (int yy2 = y0; yy2 <= y1; ++yy2)
                    for (int xx2 = x0; xx2 <= x1; ++xx2) {
                        const int c2 = yy2 * GRID_DIM + xx2;
                        const int e2 = cstart[c2 + 1];
                        for (int s2 = cstart[c2]; s2 < e2; ++s2) {
                            int j2 = sidx[s2];
                            if (j2 <= i || j2 >= j) continue;
                            float rs2 = ri + sr[s2];
                            if (fabsf(xi - sx[s2]) <= rs2 && fabsf(yi - sy[s2]) <= rs2)
                                ++rank;
                        }
                    }
                int g = g0 + rank;
                if (g < LB) cand[g] = (i << 13) | j;
            }
        }
}

__global__ void narrow_kernel(const float2* __restrict__ centers,
                              const float* __restrict__ radii,
                              const int* __restrict__ rstart,
                              const int* __restrict__ LBp,
                              const int* __restrict__ cand,
                              unsigned long long* __restrict__ hitbits) {
    int t = blockIdx.x * blockDim.x + threadIdx.x;
    if (t >= MAXB) return;
    const int total = rstart[NB];
    const int LB = *LBp;
    bool hit = false;
    if (t < total && t < LB) {
        int p = cand[t];
        int i = p >> 13, j = p & (NB - 1);
        float2 ci = centers[i], cj = centers[j];
        float dx = cj.x - ci.x, dy = cj.y - ci.y;
        float rs = radii[i] + radii[j];
        float dist = sqrtf(dx * dx + dy * dy + EPS);
        hit = (rs - dist) > 0.0f;
    }
    unsigned long long m = __ballot(hit);
    if ((threadIdx.x & 63) == 0) hitbits[t >> 6] = m;
}

__global__ __launch_bounds__(512) void wordscan_kernel(
        const unsigned long long* __restrict__ bits, int* __restrict__ wstart) {
    __shared__ int bs[512];
    const int t = threadIdx.x;
    bs[t] = __popcll(bits[t]);
    __syncthreads();
    for (int off = 1; off < 512; off <<= 1) {
        int add = (t >= off) ? bs[t - off] : 0;
        __syncthreads();
        if (t >= off) bs[t] += add;
        __syncthreads();
    }
    wstart[t] = (t == 0) ? 0 : bs[t - 1];
}

__global__ void resolve_kernel(const float2* __restrict__ centers,
                               const float* __restrict__ radii,
                               const int* __restrict__ rstart,
                               const int* __restrict__ LBp,
                               const int* __restrict__ LNp,
                               const int* __restrict__ cand,
                               const unsigned long long* __restrict__ hitbits,
                               const int* __restrict__ wstart,
                               float* __restrict__ out) {
    int t = blockIdx.x * blockDim.x + threadIdx.x;
    if (t >= MAXB) return;
    const int total = rstart[NB];
    const int LB = *LBp;
    if (t >= total || t >= LB) return;
    unsigned long long w = hitbits[t >> 6];
    if (!((w >> (t & 63)) & 1ull)) return;
    int rank = wstart[t >> 6] + __popcll(w & ((1ull << (t & 63)) - 1ull));
    if (rank >= *LNp) return;
    int p = cand[t];
    int i = p >> 13, j = p & (NB - 1);
    float2 ci = centers[i], cj = centers[j];
    float dx = cj.x - ci.x, dy = cj.y - ci.y;
    float rs = radii[i] + radii[j];
    float dist = sqrtf(dx * dx + dy * dy + EPS);
    float s = 0.5f * (rs - dist) / dist;
    float px = s * dx, py = s * dy;
    atomicAdd(&out[2 * i], -px);
    atomicAdd(&out[2 * i + 1], -py);
    atomicAdd(&out[2 * j], px);
    atomicAdd(&out[2 * j + 1], py);
}

extern "C" void kernel_launch(void* const* d_in, const int* in_sizes, int n_in,
                              void* d_out, int out_size, void* d_ws, size_t ws_size,
                              hipStream_t stream) {
    const float* centers = (const float*)d_in[0];
    const float* radii   = (const float*)d_in[1];
    const int* LBp = (const int*)d_in[2];
    const int* LNp = (const int*)d_in[3];
    float* out = (float*)d_out;

    int* ws = (int*)d_ws;
    unsigned long long* hitbits = (unsigned long long*)(ws + O_HITBITS);
    int* wstart = ws + O_WSTART;
    int* ccount = ws + O_CCOUNT;
    int* cfill  = ws + O_CFILL;
    int* cstart = ws + O_CSTART;
    int* sidx   = ws + O_SIDX;
    float* sx   = (float*)(ws + O_SX);
    float* sy   = (float*)(ws + O_SY);
    float* sr   = (float*)(ws + O_SR);
    int* rcount = ws + O_RCOUNT;
    int* rstart = ws + O_RSTART;
    int* cand   = ws + O_CAND;

    const float2* c2 = (const float2*)centers;

    // out = centers (then scatter deltas on top); zero the cell counters
    hipMemcpyAsync(out, centers, NB * 2 * sizeof(float),
                   hipMemcpyDeviceToDevice, stream);
    hipMemsetAsync(ccount, 0, 2 * NCELLS * sizeof(int), stream);  // ccount+cfill

    cell_count_kernel<<<NB / 256, 256, 0, stream>>>(c2, ccount);
    scan_kernel<1024, 4><<<1, 1024, 0, stream>>>(ccount, cstart, NCELLS);
    scatter_kernel<<<NB / 256, 256, 0, stream>>>(c2, radii, cstart, cfill,
                                                 sidx, sx, sy, sr);
    broad_count_kernel<<<NB / 256, 256, 0, stream>>>(cstart, sidx, sx, sy, sr,
                                                     rcount);
    scan_kernel<1024, 8><<<1, 1024, 0, stream>>>(rcount, rstart, NB);
    emit_kernel<<<NB / 256, 256, 0, stream>>>(cstart, sidx, sx, sy, sr,
                                              rstart, LBp, cand);
    narrow_kernel<<<MAXB / 256, 256, 0, stream>>>(c2, radii, rstart, LBp,
                                                  cand, hitbits);
    wordscan_kernel<<<1, 512, 0, stream>>>(hitbits, wstart);
    resolve_kernel<<<MAXB / 256, 256, 0, stream>>>(c2, radii, rstart, LBp, LNp,
                                                   cand, hitbits, wstart, out);
}

// Round 3
// 151.404 us; speedup vs baseline: 3.2671x; 3.2671x over previous
//
#include <hip/hip_runtime.h>

// NaiveCollider: uniform-grid broad phase; exact jnp.nonzero ordered-compaction
// semantics via per-row counts + scans; ranks computed ONLY for the (<=2)
// truncation-boundary rows (eligibility is a j-prefix within a row).

constexpr int NB = 8192;
constexpr int GRID_DIM = 56;              // cell 2.0 >= max rsum; 112/2
constexpr int NCELLS = GRID_DIM * GRID_DIM;
constexpr float INV_CELL = 0.5f;
constexpr float EPS = 1e-12f;

// workspace int offsets
constexpr int O_CCOUNT = 0;                                   // 3136
constexpr int O_CFILL  = O_CCOUNT + NCELLS;                   // 3136
constexpr int O_CSTART = O_CFILL + NCELLS;                    // 3137
constexpr int O_SORT   = (O_CSTART + NCELLS + 1 + 3) & ~3;    // float4[NB], 16B-aligned
constexpr int O_RCOUNT = O_SORT + 4 * NB;                     // 8192
constexpr int O_RSTART = O_RCOUNT + NB;                       // 8193
constexpr int O_HRAW   = O_RSTART + NB + 1;                   // 8192
constexpr int O_HCOUNT = O_HRAW + NB;                         // 8192
constexpr int O_HSTART = O_HCOUNT + NB;                       // 8193

__device__ __forceinline__ int cell_of(float v) {
    int c = (int)(v * INV_CELL);
    return c > GRID_DIM - 1 ? GRID_DIM - 1 : (c < 0 ? 0 : c);
}

__global__ void cell_count_kernel(const float2* __restrict__ centers,
                                  int* __restrict__ ccount) {
    int t = blockIdx.x * blockDim.x + threadIdx.x;
    if (t >= NB) return;
    float2 c = centers[t];
    atomicAdd(&ccount[cell_of(c.y) * GRID_DIM + cell_of(c.x)], 1);
}

template <int TPB, int IPT>
__global__ __launch_bounds__(TPB) void scan_kernel(const int* __restrict__ in,
                                                   int* __restrict__ out, int n) {
    __shared__ int bs[TPB];
    const int t = threadIdx.x;
    int v[IPT];
    int local = 0;
    const int base = t * IPT;
#pragma unroll
    for (int k = 0; k < IPT; ++k) {
        int idx = base + k;
        v[k] = (idx < n) ? in[idx] : 0;
        local += v[k];
    }
    bs[t] = local;
    __syncthreads();
    for (int off = 1; off < TPB; off <<= 1) {
        int add = (t >= off) ? bs[t - off] : 0;
        __syncthreads();
        if (t >= off) bs[t] += add;
        __syncthreads();
    }
    int run = (t == 0) ? 0 : bs[t - 1];
#pragma unroll
    for (int k = 0; k < IPT; ++k) {
        int idx = base + k;
        if (idx < n) out[idx] = run;
        run += v[k];
    }
    if (t == TPB - 1) out[n] = bs[TPB - 1];
}

__global__ void scatter_kernel(const float2* __restrict__ centers,
                               const float* __restrict__ radii,
                               const int* __restrict__ cstart,
                               int* __restrict__ cfill,
                               float4* __restrict__ sorted) {
    int t = blockIdx.x * blockDim.x + threadIdx.x;
    if (t >= NB) return;
    float2 c = centers[t];
    int cell = cell_of(c.y) * GRID_DIM + cell_of(c.x);
    int s = cstart[cell] + atomicAdd(&cfill[cell], 1);
    sorted[s] = make_float4(c.x, c.y, radii[t], __int_as_float(t));
}

// Per body (sorted order): broad count + raw hit count. Flat 3-segment scan,
// no ordering, low divergence.
__global__ void count_kernel(const int* __restrict__ cstart,
                             const float4* __restrict__ sorted,
                             int* __restrict__ rcount, int* __restrict__ hraw) {
    int t = blockIdx.x * blockDim.x + threadIdx.x;
    if (t >= NB) return;
    const float4 me = sorted[t];
    const int i = __float_as_int(me.w);
    const int cx = cell_of(me.x), cy = cell_of(me.y);
    const int x0 = max(cx - 1, 0), x1 = min(cx + 1, GRID_DIM - 1);
    const int y0 = max(cy - 1, 0), y1 = min(cy + 1, GRID_DIM - 1);
    int rc = 0, hc = 0;
    for (int yy = y0; yy <= y1; ++yy) {
        const int s0 = cstart[yy * GRID_DIM + x0];
        const int s1 = cstart[yy * GRID_DIM + x1 + 1];
        for (int s = s0; s < s1; ++s) {
            const float4 o = sorted[s];
            const int j = __float_as_int(o.w);
            if (j <= i) continue;
            const float rs = me.z + o.z;
            const float dx = o.x - me.x, dy = o.y - me.y;
            if (fabsf(dx) <= rs && fabsf(dy) <= rs) {
                ++rc;
                const float dist = sqrtf(dx * dx + dy * dy + EPS);
                if (rs - dist > 0.0f) ++hc;
            }
        }
    }
    rcount[i] = rc;
    hraw[i] = hc;
}

// Adjust per-row hit counts for broad truncation (only the <=1 boundary row
// needs the O(k^2) rescan).
__global__ void hadjust_kernel(const int* __restrict__ cstart,
                               const float4* __restrict__ sorted,
                               const int* __restrict__ rcount,
                               const int* __restrict__ rstart,
                               const int* __restrict__ hraw,
                               const int* __restrict__ LBp,
                               int* __restrict__ hcount) {
    int t = blockIdx.x * blockDim.x + threadIdx.x;
    if (t >= NB) return;
    const float4 me = sorted[t];
    const int i = __float_as_int(me.w);
    const int LB = *LBp;
    const int bstart = rstart[i];
    const int bcnt = rcount[i];
    if (bstart + bcnt <= LB) { hcount[i] = hraw[i]; return; }
    if (bstart >= LB) { hcount[i] = 0; return; }
    // boundary row: candidates with j-ordered broad rank < LB-bstart are eligible
    const int lim = LB - bstart;
    const int cx = cell_of(me.x), cy = cell_of(me.y);
    const int x0 = max(cx - 1, 0), x1 = min(cx + 1, GRID_DIM - 1);
    const int y0 = max(cy - 1, 0), y1 = min(cy + 1, GRID_DIM - 1);
    int h = 0;
    for (int yy = y0; yy <= y1; ++yy) {
        const int s0 = cstart[yy * GRID_DIM + x0];
        const int s1 = cstart[yy * GRID_DIM + x1 + 1];
        for (int s = s0; s < s1; ++s) {
            const float4 o = sorted[s];
            const int j = __float_as_int(o.w);
            if (j <= i) continue;
            const float rs = me.z + o.z;
            const float dx = o.x - me.x, dy = o.y - me.y;
            if (!(fabsf(dx) <= rs && fabsf(dy) <= rs)) continue;
            int brank = 0;  // overlapping j' with i < j' < j
            for (int yy2 = y0; yy2 <= y1; ++yy2) {
                const int t0 = cstart[yy2 * GRID_DIM + x0];
                const int t1 = cstart[yy2 * GRID_DIM + x1 + 1];
                for (int s2 = t0; s2 < t1; ++s2) {
                    const float4 o2 = sorted[s2];
                    const int j2 = __float_as_int(o2.w);
                    if (j2 <= i || j2 >= j) continue;
                    const float rs2 = me.z + o2.z;
                    if (fabsf(o2.x - me.x) <= rs2 && fabsf(o2.y - me.y) <= rs2)
                        ++brank;
                }
            }
            if (brank < lim) {
                const float dist = sqrtf(dx * dx + dy * dy + EPS);
                if (rs - dist > 0.0f) ++h;
            }
        }
    }
    hcount[i] = h;
}

__global__ void resolve_kernel(const int* __restrict__ cstart,
                               const float4* __restrict__ sorted,
                               const int* __restrict__ rcount,
                               const int* __restrict__ rstart,
                               const int* __restrict__ hcount,
                               const int* __restrict__ hstart,
                               const int* __restrict__ LBp,
                               const int* __restrict__ LNp,
                               float* __restrict__ out) {
    int t = blockIdx.x * blockDim.x + threadIdx.x;
    if (t >= NB) return;
    const float4 me = sorted[t];
    const int i = __float_as_int(me.w);
    const int LB = *LBp, LN = *LNp;
    const int bstart = rstart[i], bcnt = rcount[i];
    const int h0 = hstart[i], hcnt = hcount[i];
    if (hcnt == 0 || h0 >= LN) return;
    const bool fast = (bstart + bcnt <= LB) && (h0 + hcnt <= LN);
    const int cx = cell_of(me.x), cy = cell_of(me.y);
    const int x0 = max(cx - 1, 0), x1 = min(cx + 1, GRID_DIM - 1);
    const int y0 = max(cy - 1, 0), y1 = min(cy + 1, GRID_DIM - 1);
    float accx = 0.f, accy = 0.f;
    for (int yy = y0; yy <= y1; ++yy) {
        const int s0 = cstart[yy * GRID_DIM + x0];
        const int s1 = cstart[yy * GRID_DIM + x1 + 1];
        for (int s = s0; s < s1; ++s) {
            const float4 o = sorted[s];
            const int j = __float_as_int(o.w);
            if (j <= i) continue;
            const float rs = me.z + o.z;
            const float dx = o.x - me.x, dy = o.y - me.y;
            if (!(fabsf(dx) <= rs && fabsf(dy) <= rs)) continue;
            const float dist = sqrtf(dx * dx + dy * dy + EPS);
            const float depth = rs - dist;
            if (depth <= 0.0f) continue;
            bool apply = fast;
            if (!fast) {
                // j-ordered ranks among this row's candidates (prefix property:
                // eligibility and hit-rank are consistent, see analysis)
                int brank = 0, hrank = 0;
                for (int yy2 = y0; yy2 <= y1; ++yy2) {
                    const int t0 = cstart[yy2 * GRID_DIM + x0];
                    const int t1 = cstart[yy2 * GRID_DIM + x1 + 1];
                    for (int s2 = t0; s2 < t1; ++s2) {
                        const float4 o2 = sorted[s2];
                        const int j2 = __float_as_int(o2.w);
                        if (j2 <= i || j2 >= j) continue;
                        const float rs2 = me.z + o2.z;
                        const float dx2 = o2.x - me.x, dy2 = o2.y - me.y;
                        if (fabsf(dx2) <= rs2 && fabsf(dy2) <= rs2) {
                            ++brank;
                            const float d2 = sqrtf(dx2 * dx2 + dy2 * dy2 + EPS);
                            if (rs2 - d2 > 0.0f) ++hrank;
                        }
                    }
                }
                apply = (bstart + brank < LB) && (h0 + hrank < LN);
            }
            if (apply) {
                const float sc = 0.5f * depth / dist;
                const float px = sc * dx, py = sc * dy;
                accx -= px;
                accy -= py;
                atomicAdd(&out[2 * j], px);
                atomicAdd(&out[2 * j + 1], py);
            }
        }
    }
    if (accx != 0.f || accy != 0.f) {
        atomicAdd(&out[2 * i], accx);
        atomicAdd(&out[2 * i + 1], accy);
    }
}

extern "C" void kernel_launch(void* const* d_in, const int* in_sizes, int n_in,
                              void* d_out, int out_size, void* d_ws, size_t ws_size,
                              hipStream_t stream) {
    const float* centers = (const float*)d_in[0];
    const float* radii   = (const float*)d_in[1];
    const int* LBp = (const int*)d_in[2];
    const int* LNp = (const int*)d_in[3];
    float* out = (float*)d_out;

    int* ws = (int*)d_ws;
    int* ccount = ws + O_CCOUNT;
    int* cfill  = ws + O_CFILL;
    int* cstart = ws + O_CSTART;
    float4* sorted = (float4*)(ws + O_SORT);
    int* rcount = ws + O_RCOUNT;
    int* rstart = ws + O_RSTART;
    int* hraw   = ws + O_HRAW;
    int* hcount = ws + O_HCOUNT;
    int* hstart = ws + O_HSTART;

    const float2* c2 = (const float2*)centers;

    hipMemcpyAsync(out, centers, NB * 2 * sizeof(float),
                   hipMemcpyDeviceToDevice, stream);
    hipMemsetAsync(ccount, 0, 2 * NCELLS * sizeof(int), stream);  // ccount+cfill

    cell_count_kernel<<<NB / 256, 256, 0, stream>>>(c2, ccount);
    scan_kernel<1024, 4><<<1, 1024, 0, stream>>>(ccount, cstart, NCELLS);
    scatter_kernel<<<NB / 256, 256, 0, stream>>>(c2, radii, cstart, cfill, sorted);
    count_kernel<<<NB / 64, 64, 0, stream>>>(cstart, sorted, rcount, hraw);
    scan_kernel<1024, 8><<<1, 1024, 0, stream>>>(rcount, rstart, NB);
    hadjust_kernel<<<NB / 64, 64, 0, stream>>>(cstart, sorted, rcount, rstart,
                                               hraw, LBp, hcount);
    scan_kernel<1024, 8><<<1, 1024, 0, stream>>>(hcount, hstart, NB);
    resolve_kernel<<<NB / 64, 64, 0, stream>>>(cstart, sorted, rcount, rstart,
                                               hcount, hstart, LBp, LNp, out);
}

// Round 4
// 122.147 us; speedup vs baseline: 4.0497x; 1.2395x over previous
//
#include <hip/hip_runtime.h>

// NaiveCollider: uniform-grid broad phase, exact jnp.nonzero ordered-compaction
// semantics. 4 dispatches total:
//   build (1 block)  : LDS histogram + scan + counting-sort scatter
//   count (wide)     : per-row broad/hit counts, + out=centers copy
//   scan  (1 block)  : both row scans, per-row status, wave-parallel resolve
//                      of the <=2 truncation-boundary rows
//   resolve (wide)   : fast rows only (apply all their hits), no rank logic
// The round-3 50us tail was one thread serially rescanning the narrow-cap
// boundary row; that row is now handled by a full wave inside scan_kernel.

constexpr int NB = 8192;
constexpr int GRID_DIM = 56;              // cell 2.0 >= max rsum; 112/2
constexpr int NCELLS = GRID_DIM * GRID_DIM;
constexpr float INV_CELL = 0.5f;
constexpr float EPS = 1e-12f;

// workspace int offsets
constexpr int O_CSTART = 0;                                // 3137
constexpr int O_SORT   = (O_CSTART + NCELLS + 1 + 3) & ~3; // float4[NB]
constexpr int O_RCOUNT = O_SORT + 4 * NB;                  // 8192
constexpr int O_HRAW   = O_RCOUNT + NB;                    // 8192
constexpr int O_STATUS = O_HRAW + NB;                      // 8192

__device__ __forceinline__ int cell_of(float v) {
    int c = (int)(v * INV_CELL);
    return c > GRID_DIM - 1 ? GRID_DIM - 1 : (c < 0 ? 0 : c);
}

__global__ __launch_bounds__(1024) void build_kernel(
        const float2* __restrict__ centers, const float* __restrict__ radii,
        int* __restrict__ g_cstart, float4* __restrict__ sorted) {
    __shared__ int hist[NCELLS];
    __shared__ int bs[1024];
    const int t = threadIdx.x;
    for (int k = t; k < NCELLS; k += 1024) hist[k] = 0;
    __syncthreads();
    float2 c[8]; float r[8]; int cell[8];
#pragma unroll
    for (int k = 0; k < 8; ++k) {
        const int idx = k * 1024 + t;
        c[k] = centers[idx];
        r[k] = radii[idx];
        cell[k] = cell_of(c[k].y) * GRID_DIM + cell_of(c[k].x);
        atomicAdd(&hist[cell[k]], 1);
    }
    __syncthreads();
    // exclusive scan of hist (3136 entries, 4 per thread)
    int v[4]; int local = 0;
    const int base = t * 4;
#pragma unroll
    for (int k = 0; k < 4; ++k) {
        const int idx = base + k;
        v[k] = (idx < NCELLS) ? hist[idx] : 0;
        local += v[k];
    }
    bs[t] = local;
    __syncthreads();
    for (int off = 1; off < 1024; off <<= 1) {
        int add = (t >= off) ? bs[t - off] : 0;
        __syncthreads();
        if (t >= off) bs[t] += add;
        __syncthreads();
    }
    int run = (t == 0) ? 0 : bs[t - 1];
#pragma unroll
    for (int k = 0; k < 4; ++k) {
        const int idx = base + k;
        if (idx < NCELLS) { g_cstart[idx] = run; hist[idx] = run; }  // hist -> cfill
        run += v[k];
    }
    if (t == 1023) g_cstart[NCELLS] = run;
    __syncthreads();
#pragma unroll
    for (int k = 0; k < 8; ++k) {
        const int slot = atomicAdd(&hist[cell[k]], 1);
        const int idx = k * 1024 + t;
        sorted[slot] = make_float4(c[k].x, c[k].y, r[k], __int_as_float(idx));
    }
}

__global__ void count_kernel(const float2* __restrict__ centers,
                             const int* __restrict__ cstart,
                             const float4* __restrict__ sorted,
                             int* __restrict__ rcount, int* __restrict__ hraw,
                             float2* __restrict__ out2) {
    const int t = blockIdx.x * blockDim.x + threadIdx.x;
    if (t >= NB) return;
    out2[t] = centers[t];  // fused out = centers copy
    const float4 me = sorted[t];
    const int i = __float_as_int(me.w);
    const int cx = cell_of(me.x), cy = cell_of(me.y);
    const int x0 = max(cx - 1, 0), x1 = min(cx + 1, GRID_DIM - 1);
    const int y0 = max(cy - 1, 0), y1 = min(cy + 1, GRID_DIM - 1);
    int rc = 0, hc = 0;
    for (int yy = y0; yy <= y1; ++yy) {
        const int s0 = cstart[yy * GRID_DIM + x0];
        const int s1 = cstart[yy * GRID_DIM + x1 + 1];
        for (int s = s0; s < s1; ++s) {
            const float4 o = sorted[s];
            if (__float_as_int(o.w) <= i) continue;
            const float rs = me.z + o.z;
            const float dx = o.x - me.x, dy = o.y - me.y;
            if (fabsf(dx) <= rs && fabsf(dy) <= rs) {
                ++rc;
                if (rs - sqrtf(dx * dx + dy * dy + EPS) > 0.f) ++hc;
            }
        }
    }
    rcount[i] = rc;
    hraw[i] = hc;
}

// Serial fallback: hit count of a broad-cap boundary row (unreached when
// total broad pairs <= LB, which holds for this input).
__device__ int slow_boundary_hits(const int* cstart, const float4* sorted,
                                  const float2* centers, const float* radii,
                                  int i, int lim) {
    const float2 ci = centers[i];
    const float ri = radii[i];
    const int cx = cell_of(ci.x), cy = cell_of(ci.y);
    const int x0 = max(cx - 1, 0), x1 = min(cx + 1, GRID_DIM - 1);
    const int y0 = max(cy - 1, 0), y1 = min(cy + 1, GRID_DIM - 1);
    int h = 0;
    for (int yy = y0; yy <= y1; ++yy) {
        const int s0 = cstart[yy * GRID_DIM + x0], s1 = cstart[yy * GRID_DIM + x1 + 1];
        for (int s = s0; s < s1; ++s) {
            const float4 o = sorted[s];
            const int j = __float_as_int(o.w);
            if (j <= i) continue;
            const float rs = ri + o.z, dx = o.x - ci.x, dy = o.y - ci.y;
            if (!(fabsf(dx) <= rs && fabsf(dy) <= rs)) continue;
            int brank = 0;
            for (int yy2 = y0; yy2 <= y1; ++yy2) {
                const int t0 = cstart[yy2 * GRID_DIM + x0], t1 = cstart[yy2 * GRID_DIM + x1 + 1];
                for (int s2 = t0; s2 < t1; ++s2) {
                    const float4 o2 = sorted[s2];
                    const int j2 = __float_as_int(o2.w);
                    if (j2 <= i || j2 >= j) continue;
                    const float rs2 = ri + o2.z;
                    if (fabsf(o2.x - ci.x) <= rs2 && fabsf(o2.y - ci.y) <= rs2) ++brank;
                }
            }
            if (brank < lim && rs - sqrtf(dx * dx + dy * dy + EPS) > 0.f) ++h;
        }
    }
    return h;
}

__global__ __launch_bounds__(1024) void scan_kernel(
        const float2* __restrict__ centers, const float* __restrict__ radii,
        const int* __restrict__ cstart, const float4* __restrict__ sorted,
        const int* __restrict__ rcount, const int* __restrict__ hraw,
        const int* __restrict__ LBp, const int* __restrict__ LNp,
        int* __restrict__ status, float* __restrict__ out) {
    __shared__ int bs[1024];
    __shared__ int spec_n;
    __shared__ int spec_row[2], spec_bst[2], spec_h0[2];
    const int t = threadIdx.x;
    const int LB = *LBp, LN = *LNp;
    const int base = t * 8;
    int rc[8]; int rsum = 0;
#pragma unroll
    for (int k = 0; k < 8; ++k) { rc[k] = rcount[base + k]; rsum += rc[k]; }
    bs[t] = rsum;
    __syncthreads();
    for (int off = 1; off < 1024; off <<= 1) {
        int add = (t >= off) ? bs[t - off] : 0;
        __syncthreads();
        if (t >= off) bs[t] += add;
        __syncthreads();
    }
    int run = (t == 0) ? 0 : bs[t - 1];
    int bst[8];
#pragma unroll
    for (int k = 0; k < 8; ++k) { bst[k] = run; run += rc[k]; }
    if (t == 0) spec_n = 0;
    int hc[8]; int hsum = 0;
#pragma unroll
    for (int k = 0; k < 8; ++k) {
        const int i = base + k;
        if (bst[k] >= LB) hc[k] = 0;
        else if (bst[k] + rc[k] <= LB) hc[k] = hraw[i];
        else hc[k] = slow_boundary_hits(cstart, sorted, centers, radii, i, LB - bst[k]);
        hsum += hc[k];
    }
    __syncthreads();  // spec_n visible; bs free
    bs[t] = hsum;
    __syncthreads();
    for (int off = 1; off < 1024; off <<= 1) {
        int add = (t >= off) ? bs[t - off] : 0;
        __syncthreads();
        if (t >= off) bs[t] += add;
        __syncthreads();
    }
    run = (t == 0) ? 0 : bs[t - 1];
#pragma unroll
    for (int k = 0; k < 8; ++k) {
        const int i = base + k;
        const int h0 = run; run += hc[k];
        int st = 0;
        if (hc[k] > 0 && h0 < LN) {
            const bool bfast = (bst[k] + rc[k] <= LB);
            const bool nfast = (h0 + hc[k] <= LN);
            if (bfast && nfast) st = 1;
            else {
                const int n = atomicAdd(&spec_n, 1);
                if (n < 2) { spec_row[n] = i; spec_bst[n] = bst[k]; spec_h0[n] = h0; }
            }
        }
        status[i] = st;
    }
    __syncthreads();
    if (t >= 64) return;
    // wave 0: exact j-ordered rank resolve for the <=2 boundary rows
    const int ns = min(spec_n, 2);
    const int lane = t;
    for (int sp = 0; sp < ns; ++sp) {
        const int i = spec_row[sp];
        const int blim = LB - spec_bst[sp];
        const int h0 = spec_h0[sp];
        const float2 ci = centers[i];
        const float ri = radii[i];
        const int cx = cell_of(ci.x), cy = cell_of(ci.y);
        const int x0 = max(cx - 1, 0), x1 = min(cx + 1, GRID_DIM - 1);
        const int y0 = max(cy - 1, 0), y1 = min(cy + 1, GRID_DIM - 1);
        int seg0[3], slen[3], nseg = 0, K = 0;
        for (int yy = y0; yy <= y1; ++yy) {
            const int s0 = cstart[yy * GRID_DIM + x0];
            const int s1 = cstart[yy * GRID_DIM + x1 + 1];
            seg0[nseg] = s0; slen[nseg] = s1 - s0; K += s1 - s0; ++nseg;
        }
        float accx = 0.f, accy = 0.f;
        for (int cb = 0; cb < K; cb += 64) {
            const int e = cb + lane;
            const bool ok = e < K;
            int s = 0;
            if (ok) {
                int r = e;
                for (int g = 0; g < nseg; ++g) {
                    if (r < slen[g]) { s = seg0[g] + r; break; }
                    r -= slen[g];
                }
            }
            const float4 o = ok ? sorted[s] : make_float4(0, 0, 0, __int_as_float(-1));
            const int j = __float_as_int(o.w);
            const float rs = ri + o.z, dx = o.x - ci.x, dy = o.y - ci.y;
            const bool ov = ok && j > i && fabsf(dx) <= rs && fabsf(dy) <= rs;
            if (ov) {
                const float dist = sqrtf(dx * dx + dy * dy + EPS);
                const float depth = rs - dist;
                int brank = 0, hrank = 0;
                for (int e2 = 0; e2 < K; ++e2) {  // uniform loop, broadcast loads
                    int r2 = e2, s2 = 0;
                    for (int g = 0; g < nseg; ++g) {
                        if (r2 < slen[g]) { s2 = seg0[g] + r2; break; }
                        r2 -= slen[g];
                    }
                    const float4 o2 = sorted[s2];
                    const int j2 = __float_as_int(o2.w);
                    if (j2 <= i || j2 >= j) continue;
                    const float rs2 = ri + o2.z;
                    const float dx2 = o2.x - ci.x, dy2 = o2.y - ci.y;
                    if (fabsf(dx2) <= rs2 && fabsf(dy2) <= rs2) {
                        ++brank;
                        if (rs2 - sqrtf(dx2 * dx2 + dy2 * dy2 + EPS) > 0.f) ++hrank;
                    }
                }
                if (depth > 0.f && brank < blim && h0 + hrank < LN) {
                    const float sc = 0.5f * depth / dist;
                    const float px = sc * dx, py = sc * dy;
                    accx -= px; accy -= py;
                    atomicAdd(&out[2 * j], px);
                    atomicAdd(&out[2 * j + 1], py);
                }
            }
        }
#pragma unroll
        for (int off = 32; off > 0; off >>= 1) {
            accx += __shfl_down(accx, off);
            accy += __shfl_down(accy, off);
        }
        if (lane == 0 && (accx != 0.f || accy != 0.f)) {
            atomicAdd(&out[2 * i], accx);
            atomicAdd(&out[2 * i + 1], accy);
        }
    }
}

__global__ void resolve_kernel(const int* __restrict__ cstart,
                               const float4* __restrict__ sorted,
                               const int* __restrict__ status,
                               float* __restrict__ out) {
    const int t = blockIdx.x * blockDim.x + threadIdx.x;
    if (t >= NB) return;
    const float4 me = sorted[t];
    const int i = __float_as_int(me.w);
    if (status[i] == 0) return;
    const int cx = cell_of(me.x), cy = cell_of(me.y);
    const int x0 = max(cx - 1, 0), x1 = min(cx + 1, GRID_DIM - 1);
    const int y0 = max(cy - 1, 0), y1 = min(cy + 1, GRID_DIM - 1);
    float accx = 0.f, accy = 0.f;
    for (int yy = y0; yy <= y1; ++yy) {
        const int s0 = cstart[yy * GRID_DIM + x0];
        const int s1 = cstart[yy * GRID_DIM + x1 + 1];
        for (int s = s0; s < s1; ++s) {
            const float4 o = sorted[s];
            if (__float_as_int(o.w) <= i) continue;
            const int j = __float_as_int(o.w);
            const float rs = me.z + o.z;
            const float dx = o.x - me.x, dy = o.y - me.y;
            if (!(fabsf(dx) <= rs && fabsf(dy) <= rs)) continue;
            const float dist = sqrtf(dx * dx + dy * dy + EPS);
            const float depth = rs - dist;
            if (depth <= 0.f) continue;
            const float sc = 0.5f * depth / dist;
            const float px = sc * dx, py = sc * dy;
            accx -= px; accy -= py;
            atomicAdd(&out[2 * j], px);
            atomicAdd(&out[2 * j + 1], py);
        }
    }
    if (accx != 0.f || accy != 0.f) {
        atomicAdd(&out[2 * i], accx);
        atomicAdd(&out[2 * i + 1], accy);
    }
}

extern "C" void kernel_launch(void* const* d_in, const int* in_sizes, int n_in,
                              void* d_out, int out_size, void* d_ws, size_t ws_size,
                              hipStream_t stream) {
    const float* centers = (const float*)d_in[0];
    const float* radii   = (const float*)d_in[1];
    const int* LBp = (const int*)d_in[2];
    const int* LNp = (const int*)d_in[3];
    float* out = (float*)d_out;

    int* ws = (int*)d_ws;
    int* cstart = ws + O_CSTART;
    float4* sorted = (float4*)(ws + O_SORT);
    int* rcount = ws + O_RCOUNT;
    int* hraw   = ws + O_HRAW;
    int* status = ws + O_STATUS;

    const float2* c2 = (const float2*)centers;

    build_kernel<<<1, 1024, 0, stream>>>(c2, radii, cstart, sorted);
    count_kernel<<<NB / 64, 64, 0, stream>>>(c2, cstart, sorted, rcount, hraw,
                                             (float2*)out);
    scan_kernel<<<1, 1024, 0, stream>>>(c2, radii, cstart, sorted, rcount, hraw,
                                        LBp, LNp, status, out);
    resolve_kernel<<<NB / 64, 64, 0, stream>>>(cstart, sorted, status, out);
}

// Round 5
// 114.058 us; speedup vs baseline: 4.3369x; 1.0709x over previous
//
#include <hip/hip_runtime.h>

// NaiveCollider: uniform-grid broad phase, exact jnp.nonzero ordered-compaction
// semantics. 4 dispatches:
//   build (1 block) : LDS histogram + wave-shuffle scan + counting-sort scatter
//   count (wide)    : 3 threads/row (one per y-segment), partial counts, + out copy
//   scan  (1 block) : both row scans (wave-shuffle), status flags, wave-parallel
//                     resolve of the <=2 truncation-boundary rows
//   resolve (wide)  : fast rows only, 3 threads/row, no rank logic
// Harness floor: ~40us d_ws 0xAA re-poison (268MB @ 85% HBM peak) + restores.

constexpr int NB = 8192;
constexpr int GRID_DIM = 56;              // cell 2.0 >= max rsum; 112/2
constexpr int NCELLS = GRID_DIM * GRID_DIM;
constexpr float INV_CELL = 0.5f;
constexpr float EPS = 1e-12f;

// workspace int offsets
constexpr int O_CSTART = 0;                                // 3137
constexpr int O_SORT   = (O_CSTART + NCELLS + 1 + 3) & ~3; // float4[NB]
constexpr int O_RC3    = O_SORT + 4 * NB;                  // 3*NB
constexpr int O_HR3    = O_RC3 + 3 * NB;                   // 3*NB
constexpr int O_STATUS = O_HR3 + 3 * NB;                   // NB

__device__ __forceinline__ int cell_of(float v) {
    int c = (int)(v * INV_CELL);
    return c > GRID_DIM - 1 ? GRID_DIM - 1 : (c < 0 ? 0 : c);
}

__device__ __forceinline__ int wave_incl_scan(int v, int lane) {
#pragma unroll
    for (int off = 1; off < 64; off <<= 1) {
        int y = __shfl_up(v, off);
        if (lane >= off) v += y;
    }
    return v;
}

__global__ __launch_bounds__(1024) void build_kernel(
        const float2* __restrict__ centers, const float* __restrict__ radii,
        int* __restrict__ g_cstart, float4* __restrict__ sorted) {
    __shared__ int hist[NCELLS];
    __shared__ int wsum[16];
    const int t = threadIdx.x;
    const int lane = t & 63, wid = t >> 6;
    for (int k = t; k < NCELLS; k += 1024) hist[k] = 0;
    __syncthreads();
    float2 c[8]; float r[8]; int cell[8];
#pragma unroll
    for (int k = 0; k < 8; ++k) {
        const int idx = k * 1024 + t;
        c[k] = centers[idx];
        r[k] = radii[idx];
        cell[k] = cell_of(c[k].y) * GRID_DIM + cell_of(c[k].x);
        atomicAdd(&hist[cell[k]], 1);
    }
    __syncthreads();
    // exclusive scan of hist (4/thread) via wave shuffles: 2 barriers total
    int v[4]; int local = 0;
    const int base = t * 4;
#pragma unroll
    for (int k = 0; k < 4; ++k) {
        const int idx = base + k;
        v[k] = (idx < NCELLS) ? hist[idx] : 0;
        local += v[k];
    }
    const int incl = wave_incl_scan(local, lane);
    if (lane == 63) wsum[wid] = incl;
    __syncthreads();   // also separates hist reads (above) from writes (below)
    if (wid == 0) {
        const int orig = (lane < 16) ? wsum[lane] : 0;
        const int inc = wave_incl_scan(orig, lane);
        if (lane < 16) wsum[lane] = inc - orig;  // exclusive wave offsets
    }
    __syncthreads();
    int run = wsum[wid] + incl - local;
#pragma unroll
    for (int k = 0; k < 4; ++k) {
        const int idx = base + k;
        if (idx < NCELLS) { g_cstart[idx] = run; hist[idx] = run; }  // hist->cfill
        run += v[k];
    }
    if (t == 1023) g_cstart[NCELLS] = run;
    __syncthreads();
#pragma unroll
    for (int k = 0; k < 8; ++k) {
        const int slot = atomicAdd(&hist[cell[k]], 1);
        const int idx = k * 1024 + t;
        sorted[slot] = make_float4(c[k].x, c[k].y, r[k], __int_as_float(idx));
    }
}

// 3 threads per body: thread (seg, slot) scans y-row cy-1+seg of the 3x3
// neighborhood. Partial counts land in rc3/hr3[seg*NB + body_id].
__global__ void count_kernel(const float2* __restrict__ centers,
                             const int* __restrict__ cstart,
                             const float4* __restrict__ sorted,
                             int* __restrict__ rc3, int* __restrict__ hr3,
                             float2* __restrict__ out2) {
    const int t = blockIdx.x * blockDim.x + threadIdx.x;
    if (t < NB) out2[t] = centers[t];  // fused out = centers copy
    if (t >= 3 * NB) return;
    const int slot = t & (NB - 1);
    const int seg = t >> 13;
    const float4 me = sorted[slot];
    const int i = __float_as_int(me.w);
    const int cx = cell_of(me.x), cy = cell_of(me.y);
    const int yy = cy - 1 + seg;
    int rc = 0, hc = 0;
    if (yy >= 0 && yy < GRID_DIM) {
        const int x0 = max(cx - 1, 0), x1 = min(cx + 1, GRID_DIM - 1);
        const int s0 = cstart[yy * GRID_DIM + x0];
        const int s1 = cstart[yy * GRID_DIM + x1 + 1];
        for (int s = s0; s < s1; ++s) {
            const float4 o = sorted[s];
            if (__float_as_int(o.w) <= i) continue;
            const float rs = me.z + o.z;
            const float dx = o.x - me.x, dy = o.y - me.y;
            if (fabsf(dx) <= rs && fabsf(dy) <= rs) {
                ++rc;
                if (rs - sqrtf(dx * dx + dy * dy + EPS) > 0.f) ++hc;
            }
        }
    }
    rc3[seg * NB + i] = rc;
    hr3[seg * NB + i] = hc;
}

// Serial fallback: hit count of a broad-cap boundary row (unreached when
// total broad pairs <= LB, which holds for this input).
__device__ int slow_boundary_hits(const int* cstart, const float4* sorted,
                                  const float2* centers, const float* radii,
                                  int i, int lim) {
    const float2 ci = centers[i];
    const float ri = radii[i];
    const int cx = cell_of(ci.x), cy = cell_of(ci.y);
    const int x0 = max(cx - 1, 0), x1 = min(cx + 1, GRID_DIM - 1);
    const int y0 = max(cy - 1, 0), y1 = min(cy + 1, GRID_DIM - 1);
    int h = 0;
    for (int yy = y0; yy <= y1; ++yy) {
        const int s0 = cstart[yy * GRID_DIM + x0], s1 = cstart[yy * GRID_DIM + x1 + 1];
        for (int s = s0; s < s1; ++s) {
            const float4 o = sorted[s];
            const int j = __float_as_int(o.w);
            if (j <= i) continue;
            const float rs = ri + o.z, dx = o.x - ci.x, dy = o.y - ci.y;
            if (!(fabsf(dx) <= rs && fabsf(dy) <= rs)) continue;
            int brank = 0;
            for (int yy2 = y0; yy2 <= y1; ++yy2) {
                const int t0 = cstart[yy2 * GRID_DIM + x0], t1 = cstart[yy2 * GRID_DIM + x1 + 1];
                for (int s2 = t0; s2 < t1; ++s2) {
                    const float4 o2 = sorted[s2];
                    const int j2 = __float_as_int(o2.w);
                    if (j2 <= i || j2 >= j) continue;
                    const float rs2 = ri + o2.z;
                    if (fabsf(o2.x - ci.x) <= rs2 && fabsf(o2.y - ci.y) <= rs2) ++brank;
                }
            }
            if (brank < lim && rs - sqrtf(dx * dx + dy * dy + EPS) > 0.f) ++h;
        }
    }
    return h;
}

__global__ __launch_bounds__(1024) void scan_kernel(
        const float2* __restrict__ centers, const float* __restrict__ radii,
        const int* __restrict__ cstart, const float4* __restrict__ sorted,
        const int* __restrict__ rc3, const int* __restrict__ hr3,
        const int* __restrict__ LBp, const int* __restrict__ LNp,
        int* __restrict__ status, float* __restrict__ out) {
    __shared__ int wsum[16];
    __shared__ int spec_n;
    __shared__ int spec_row[2], spec_bst[2], spec_h0[2];
    const int t = threadIdx.x;
    const int lane = t & 63, wid = t >> 6;
    const int LB = *LBp, LN = *LNp;
    const int base = t * 8;
    if (t == 0) spec_n = 0;
    int rc[8]; int rsum = 0;
#pragma unroll
    for (int k = 0; k < 8; ++k) {
        const int i = base + k;
        rc[k] = rc3[i] + rc3[NB + i] + rc3[2 * NB + i];
        rsum += rc[k];
    }
    const int incl = wave_incl_scan(rsum, lane);
    if (lane == 63) wsum[wid] = incl;
    __syncthreads();
    if (wid == 0) {
        const int orig = (lane < 16) ? wsum[lane] : 0;
        const int inc = wave_incl_scan(orig, lane);
        if (lane < 16) wsum[lane] = inc - orig;
    }
    __syncthreads();
    int run = wsum[wid] + incl - rsum;
    int bst[8];
#pragma unroll
    for (int k = 0; k < 8; ++k) { bst[k] = run; run += rc[k]; }
    int hc[8]; int hsum = 0;
#pragma unroll
    for (int k = 0; k < 8; ++k) {
        const int i = base + k;
        if (bst[k] >= LB) hc[k] = 0;
        else if (bst[k] + rc[k] <= LB) hc[k] = hr3[i] + hr3[NB + i] + hr3[2 * NB + i];
        else hc[k] = slow_boundary_hits(cstart, sorted, centers, radii, i, LB - bst[k]);
        hsum += hc[k];
    }
    __syncthreads();  // wsum reuse
    const int incl2 = wave_incl_scan(hsum, lane);
    if (lane == 63) wsum[wid] = incl2;
    __syncthreads();
    if (wid == 0) {
        const int orig = (lane < 16) ? wsum[lane] : 0;
        const int inc = wave_incl_scan(orig, lane);
        if (lane < 16) wsum[lane] = inc - orig;
    }
    __syncthreads();
    run = wsum[wid] + incl2 - hsum;
#pragma unroll
    for (int k = 0; k < 8; ++k) {
        const int i = base + k;
        const int h0 = run; run += hc[k];
        int st = 0;
        if (hc[k] > 0 && h0 < LN) {
            const bool bfast = (bst[k] + rc[k] <= LB);
            const bool nfast = (h0 + hc[k] <= LN);
            if (bfast && nfast) st = 1;
            else {
                const int n = atomicAdd(&spec_n, 1);
                if (n < 2) { spec_row[n] = i; spec_bst[n] = bst[k]; spec_h0[n] = h0; }
            }
        }
        status[i] = st;
    }
    __syncthreads();
    if (t >= 64) return;
    // wave 0: exact j-ordered rank resolve for the <=2 boundary rows
    const int ns = min(spec_n, 2);
    for (int sp = 0; sp < ns; ++sp) {
        const int i = spec_row[sp];
        const int blim = LB - spec_bst[sp];
        const int h0 = spec_h0[sp];
        const float2 ci = centers[i];
        const float ri = radii[i];
        const int cx = cell_of(ci.x), cy = cell_of(ci.y);
        const int x0 = max(cx - 1, 0), x1 = min(cx + 1, GRID_DIM - 1);
        const int y0 = max(cy - 1, 0), y1 = min(cy + 1, GRID_DIM - 1);
        int seg0[3], slen[3], nseg = 0, K = 0;
        for (int yy = y0; yy <= y1; ++yy) {
            const int s0 = cstart[yy * GRID_DIM + x0];
            const int s1 = cstart[yy * GRID_DIM + x1 + 1];
            seg0[nseg] = s0; slen[nseg] = s1 - s0; K += s1 - s0; ++nseg;
        }
        float accx = 0.f, accy = 0.f;
        for (int cb = 0; cb < K; cb += 64) {
            const int e = cb + lane;
            const bool ok = e < K;
            int s = 0;
            if (ok) {
                int r = e;
                for (int g = 0; g < nseg; ++g) {
                    if (r < slen[g]) { s = seg0[g] + r; break; }
                    r -= slen[g];
                }
            }
            const float4 o = ok ? sorted[s] : make_float4(0, 0, 0, __int_as_float(-1));
            const int j = __float_as_int(o.w);
            const float rs = ri + o.z, dx = o.x - ci.x, dy = o.y - ci.y;
            const bool ov = ok && j > i && fabsf(dx) <= rs && fabsf(dy) <= rs;
            if (ov) {
                const float dist = sqrtf(dx * dx + dy * dy + EPS);
                const float depth = rs - dist;
                int brank = 0, hrank = 0;
                for (int e2 = 0; e2 < K; ++e2) {  // uniform loop, broadcast loads
                    int r2 = e2, s2 = 0;
                    for (int g = 0; g < nseg; ++g) {
                        if (r2 < slen[g]) { s2 = seg0[g] + r2; break; }
                        r2 -= slen[g];
                    }
                    const float4 o2 = sorted[s2];
                    const int j2 = __float_as_int(o2.w);
                    if (j2 <= i || j2 >= j) continue;
                    const float rs2 = ri + o2.z;
                    const float dx2 = o2.x - ci.x, dy2 = o2.y - ci.y;
                    if (fabsf(dx2) <= rs2 && fabsf(dy2) <= rs2) {
                        ++brank;
                        if (rs2 - sqrtf(dx2 * dx2 + dy2 * dy2 + EPS) > 0.f) ++hrank;
                    }
                }
                if (depth > 0.f && brank < blim && h0 + hrank < LN) {
                    const float sc = 0.5f * depth / dist;
                    const float px = sc * dx, py = sc * dy;
                    accx -= px; accy -= py;
                    atomicAdd(&out[2 * j], px);
                    atomicAdd(&out[2 * j + 1], py);
                }
            }
        }
#pragma unroll
        for (int off = 32; off > 0; off >>= 1) {
            accx += __shfl_down(accx, off);
            accy += __shfl_down(accy, off);
        }
        if (lane == 0 && (accx != 0.f || accy != 0.f)) {
            atomicAdd(&out[2 * i], accx);
            atomicAdd(&out[2 * i + 1], accy);
        }
    }
}

__global__ void resolve_kernel(const int* __restrict__ cstart,
                               const float4* __restrict__ sorted,
                               const int* __restrict__ status,
                               float* __restrict__ out) {
    const int t = blockIdx.x * blockDim.x + threadIdx.x;
    if (t >= 3 * NB) return;
    const int slot = t & (NB - 1);
    const int seg = t >> 13;
    const float4 me = sorted[slot];
    const int i = __float_as_int(me.w);
    if (status[i] == 0) return;
    const int cx = cell_of(me.x), cy = cell_of(me.y);
    const int yy = cy - 1 + seg;
    if (yy < 0 || yy >= GRID_DIM) return;
    const int x0 = max(cx - 1, 0), x1 = min(cx + 1, GRID_DIM - 1);
    const int s0 = cstart[yy * GRID_DIM + x0];
    const int s1 = cstart[yy * GRID_DIM + x1 + 1];
    float accx = 0.f, accy = 0.f;
    for (int s = s0; s < s1; ++s) {
        const float4 o = sorted[s];
        const int j = __float_as_int(o.w);
        if (j <= i) continue;
        const float rs = me.z + o.z;
        const float dx = o.x - me.x, dy = o.y - me.y;
        if (!(fabsf(dx) <= rs && fabsf(dy) <= rs)) continue;
        const float dist = sqrtf(dx * dx + dy * dy + EPS);
        const float depth = rs - dist;
        if (depth <= 0.f) continue;
        const float sc = 0.5f * depth / dist;
        const float px = sc * dx, py = sc * dy;
        accx -= px; accy -= py;
        atomicAdd(&out[2 * j], px);
        atomicAdd(&out[2 * j + 1], py);
    }
    if (accx != 0.f || accy != 0.f) {
        atomicAdd(&out[2 * i], accx);
        atomicAdd(&out[2 * i + 1], accy);
    }
}

extern "C" void kernel_launch(void* const* d_in, const int* in_sizes, int n_in,
                              void* d_out, int out_size, void* d_ws, size_t ws_size,
                              hipStream_t stream) {
    const float* centers = (const float*)d_in[0];
    const float* radii   = (const float*)d_in[1];
    const int* LBp = (const int*)d_in[2];
    const int* LNp = (const int*)d_in[3];
    float* out = (float*)d_out;

    int* ws = (int*)d_ws;
    int* cstart = ws + O_CSTART;
    float4* sorted = (float4*)(ws + O_SORT);
    int* rc3 = ws + O_RC3;
    int* hr3 = ws + O_HR3;
    int* status = ws + O_STATUS;

    const float2* c2 = (const float2*)centers;

    build_kernel<<<1, 1024, 0, stream>>>(c2, radii, cstart, sorted);
    count_kernel<<<3 * NB / 256, 256, 0, stream>>>(c2, cstart, sorted, rc3, hr3,
                                                   (float2*)out);
    scan_kernel<<<1, 1024, 0, stream>>>(c2, radii, cstart, sorted, rc3, hr3,
                                        LBp, LNp, status, out);
    resolve_kernel<<<3 * NB / 256, 256, 0, stream>>>(cstart, sorted, status, out);
}

// Round 6
// 111.634 us; speedup vs baseline: 4.4311x; 1.0217x over previous
//
#include <hip/hip_runtime.h>

// NaiveCollider: uniform-grid broad phase, exact jnp.nonzero ordered-compaction
// semantics. 5 dispatches:
//   memset (12.5KB) : zero per-cell counters
//   fill   (wide)   : bin bodies into fixed-capacity cell table (global atomics),
//                     zero rcomb, fused out=centers copy
//   count  (wide)   : 3 threads/body (one per y-row of 3x3 hood), packed
//                     (rc<<8|hc) atomicAdd into rcomb[body]
//   scan   (1 block): both row scans (wave shuffles), status flags, wave-parallel
//                     exact resolve of the <=2 truncation-boundary rows
//   resolve (wide)  : fast rows only (apply all hits), 3 threads/body
// Harness floor: ~40us d_ws 0xAA re-poison (268MB @ 85% HBM peak) + restores.

constexpr int NB = 8192;
constexpr int GRID_DIM = 56;              // cell 2.0 >= max rsum; 112/2
constexpr int NCELLS = GRID_DIM * GRID_DIM;
constexpr int CAP = 20;                   // max bodies/cell (Poisson mean 2.6)
constexpr float INV_CELL = 0.5f;
constexpr float EPS = 1e-12f;

// workspace int offsets
constexpr int O_CCOUNT = 0;                       // 3136
constexpr int O_RCOMB  = O_CCOUNT + NCELLS;       // 8192
constexpr int O_STATUS = O_RCOMB + NB;            // 8192
constexpr int O_CELLS  = (O_STATUS + NB + 3) & ~3; // float4[NCELLS*CAP]

__device__ __forceinline__ int cell_of(float v) {
    int c = (int)(v * INV_CELL);
    return c > GRID_DIM - 1 ? GRID_DIM - 1 : (c < 0 ? 0 : c);
}

__device__ __forceinline__ int wave_incl_scan(int v, int lane) {
#pragma unroll
    for (int off = 1; off < 64; off <<= 1) {
        int y = __shfl_up(v, off);
        if (lane >= off) v += y;
    }
    return v;
}

__global__ void fill_kernel(const float2* __restrict__ centers,
                            const float* __restrict__ radii,
                            int* __restrict__ ccount,
                            float4* __restrict__ cells,
                            int* __restrict__ rcomb,
                            float2* __restrict__ out2) {
    const int t = blockIdx.x * blockDim.x + threadIdx.x;
    if (t >= NB) return;
    const float2 c = centers[t];
    const float r = radii[t];
    out2[t] = c;        // fused out = centers copy
    rcomb[t] = 0;       // zero the packed-count accumulator (used next dispatch)
    const int cell = cell_of(c.y) * GRID_DIM + cell_of(c.x);
    const int slot = atomicAdd(&ccount[cell], 1);
    if (slot < CAP)
        cells[cell * CAP + slot] = make_float4(c.x, c.y, r, __int_as_float(t));
}

// 3 threads/body: thread (seg, body) scans y-row cy-1+seg of the 3x3 hood.
__global__ void count_kernel(const float2* __restrict__ centers,
                             const float* __restrict__ radii,
                             const int* __restrict__ ccount,
                             const float4* __restrict__ cells,
                             int* __restrict__ rcomb) {
    const int t = blockIdx.x * blockDim.x + threadIdx.x;
    if (t >= 3 * NB) return;
    const int i = t & (NB - 1);
    const int seg = t >> 13;
    const float2 ci = centers[i];
    const float ri = radii[i];
    const int cx = cell_of(ci.x), cy = cell_of(ci.y);
    const int yy = cy - 1 + seg;
    if (yy < 0 || yy >= GRID_DIM) return;
    const int x0 = max(cx - 1, 0), x1 = min(cx + 1, GRID_DIM - 1);
    int rc = 0, hc = 0;
    for (int xx = x0; xx <= x1; ++xx) {
        const int c = yy * GRID_DIM + xx;
        const int n = min(ccount[c], CAP);
        const float4* p = cells + c * CAP;
        for (int k = 0; k < n; ++k) {
            const float4 o = p[k];
            if (__float_as_int(o.w) <= i) continue;
            const float rs = ri + o.z;
            const float dx = o.x - ci.x, dy = o.y - ci.y;
            if (fabsf(dx) <= rs && fabsf(dy) <= rs) {
                ++rc;
                if (rs - sqrtf(dx * dx + dy * dy + EPS) > 0.f) ++hc;
            }
        }
    }
    if (rc | hc) atomicAdd(&rcomb[i], (rc << 8) | hc);
}

// Serial fallback: hit count of a broad-cap boundary row (unreached when
// total broad pairs <= LB, which holds for this input).
__device__ int slow_boundary_hits(const int* ccount, const float4* cells,
                                  const float2* centers, const float* radii,
                                  int i, int lim) {
    const float2 ci = centers[i];
    const float ri = radii[i];
    const int cx = cell_of(ci.x), cy = cell_of(ci.y);
    const int x0 = max(cx - 1, 0), x1 = min(cx + 1, GRID_DIM - 1);
    const int y0 = max(cy - 1, 0), y1 = min(cy + 1, GRID_DIM - 1);
    int h = 0;
    for (int yy = y0; yy <= y1; ++yy)
        for (int xx = x0; xx <= x1; ++xx) {
            const int c = yy * GRID_DIM + xx;
            const int n = min(ccount[c], CAP);
            for (int k = 0; k < n; ++k) {
                const float4 o = cells[c * CAP + k];
                const int j = __float_as_int(o.w);
                if (j <= i) continue;
                const float rs = ri + o.z, dx = o.x - ci.x, dy = o.y - ci.y;
                if (!(fabsf(dx) <= rs && fabsf(dy) <= rs)) continue;
                int brank = 0;
                for (int yy2 = y0; yy2 <= y1; ++yy2)
                    for (int xx2 = x0; xx2 <= x1; ++xx2) {
                        const int c2 = yy2 * GRID_DIM + xx2;
                        const int n2 = min(ccount[c2], CAP);
                        for (int k2 = 0; k2 < n2; ++k2) {
                            const float4 o2 = cells[c2 * CAP + k2];
                            const int j2 = __float_as_int(o2.w);
                            if (j2 <= i || j2 >= j) continue;
                            const float rs2 = ri + o2.z;
                            if (fabsf(o2.x - ci.x) <= rs2 && fabsf(o2.y - ci.y) <= rs2)
                                ++brank;
                        }
                    }
                if (brank < lim && rs - sqrtf(dx * dx + dy * dy + EPS) > 0.f) ++h;
            }
        }
    return h;
}

__global__ __launch_bounds__(1024) void scan_kernel(
        const float2* __restrict__ centers, const float* __restrict__ radii,
        const int* __restrict__ ccount, const float4* __restrict__ cells,
        const int* __restrict__ rcomb,
        const int* __restrict__ LBp, const int* __restrict__ LNp,
        int* __restrict__ status, float* __restrict__ out) {
    __shared__ int wsum[16];
    __shared__ int spec_n;
    __shared__ int spec_row[2], spec_bst[2], spec_h0[2];
    const int t = threadIdx.x;
    const int lane = t & 63, wid = t >> 6;
    const int LB = *LBp, LN = *LNp;
    const int base = t * 8;
    if (t == 0) spec_n = 0;
    int rc[8], hr[8]; int rsum = 0;
#pragma unroll
    for (int k = 0; k < 8; ++k) {
        const int v = rcomb[base + k];
        rc[k] = v >> 8;
        hr[k] = v & 0xff;
        rsum += rc[k];
    }
    const int incl = wave_incl_scan(rsum, lane);
    if (lane == 63) wsum[wid] = incl;
    __syncthreads();
    if (wid == 0) {
        const int orig = (lane < 16) ? wsum[lane] : 0;
        const int inc = wave_incl_scan(orig, lane);
        if (lane < 16) wsum[lane] = inc - orig;
    }
    __syncthreads();
    int run = wsum[wid] + incl - rsum;
    int bst[8];
#pragma unroll
    for (int k = 0; k < 8; ++k) { bst[k] = run; run += rc[k]; }
    int hc[8]; int hsum = 0;
#pragma unroll
    for (int k = 0; k < 8; ++k) {
        const int i = base + k;
        if (bst[k] >= LB) hc[k] = 0;
        else if (bst[k] + rc[k] <= LB) hc[k] = hr[k];
        else hc[k] = slow_boundary_hits(ccount, cells, centers, radii, i, LB - bst[k]);
        hsum += hc[k];
    }
    __syncthreads();  // wsum reuse
    const int incl2 = wave_incl_scan(hsum, lane);
    if (lane == 63) wsum[wid] = incl2;
    __syncthreads();
    if (wid == 0) {
        const int orig = (lane < 16) ? wsum[lane] : 0;
        const int inc = wave_incl_scan(orig, lane);
        if (lane < 16) wsum[lane] = inc - orig;
    }
    __syncthreads();
    run = wsum[wid] + incl2 - hsum;
#pragma unroll
    for (int k = 0; k < 8; ++k) {
        const int i = base + k;
        const int h0 = run; run += hc[k];
        int st = 0;
        if (hc[k] > 0 && h0 < LN) {
            const bool bfast = (bst[k] + rc[k] <= LB);
            const bool nfast = (h0 + hc[k] <= LN);
            if (bfast && nfast) st = 1;
            else {
                const int n = atomicAdd(&spec_n, 1);
                if (n < 2) { spec_row[n] = i; spec_bst[n] = bst[k]; spec_h0[n] = h0; }
            }
        }
        status[i] = st;
    }
    __syncthreads();
    if (t >= 64) return;
    // wave 0: exact j-ordered rank resolve for the <=2 boundary rows
    const int ns = min(spec_n, 2);
    for (int sp = 0; sp < ns; ++sp) {
        const int i = spec_row[sp];
        const int blim = LB - spec_bst[sp];
        const int h0 = spec_h0[sp];
        const float2 ci = centers[i];
        const float ri = radii[i];
        const int cx = cell_of(ci.x), cy = cell_of(ci.y);
        const int x0 = max(cx - 1, 0), x1 = min(cx + 1, GRID_DIM - 1);
        const int y0 = max(cy - 1, 0), y1 = min(cy + 1, GRID_DIM - 1);
        int seg0[9], slen[9], nseg = 0, K = 0;
        for (int yy = y0; yy <= y1; ++yy)
            for (int xx = x0; xx <= x1; ++xx) {
                const int c = yy * GRID_DIM + xx;
                const int n = min(ccount[c], CAP);
                if (n > 0) { seg0[nseg] = c * CAP; slen[nseg] = n; K += n; ++nseg; }
            }
        float accx = 0.f, accy = 0.f;
        for (int cb = 0; cb < K; cb += 64) {
            const int e = cb + lane;
            const bool ok = e < K;
            int s = 0;
            if (ok) {
                int r = e;
                for (int g = 0; g < nseg; ++g) {
                    if (r < slen[g]) { s = seg0[g] + r; break; }
                    r -= slen[g];
                }
            }
            const float4 o = ok ? cells[s] : make_float4(0, 0, 0, __int_as_float(-1));
            const int j = __float_as_int(o.w);
            const float rs = ri + o.z, dx = o.x - ci.x, dy = o.y - ci.y;
            const bool ov = ok && j > i && fabsf(dx) <= rs && fabsf(dy) <= rs;
            if (ov) {
                const float dist = sqrtf(dx * dx + dy * dy + EPS);
                const float depth = rs - dist;
                int brank = 0, hrank = 0;
                for (int e2 = 0; e2 < K; ++e2) {  // uniform loop, broadcast loads
                    int r2 = e2, s2 = 0;
                    for (int g = 0; g < nseg; ++g) {
                        if (r2 < slen[g]) { s2 = seg0[g] + r2; break; }
                        r2 -= slen[g];
                    }
                    const float4 o2 = cells[s2];
                    const int j2 = __float_as_int(o2.w);
                    if (j2 <= i || j2 >= j) continue;
                    const float rs2 = ri + o2.z;
                    const float dx2 = o2.x - ci.x, dy2 = o2.y - ci.y;
                    if (fabsf(dx2) <= rs2 && fabsf(dy2) <= rs2) {
                        ++brank;
                        if (rs2 - sqrtf(dx2 * dx2 + dy2 * dy2 + EPS) > 0.f) ++hrank;
                    }
                }
                if (depth > 0.f && brank < blim && h0 + hrank < LN) {
                    const float sc = 0.5f * depth / dist;
                    const float px = sc * dx, py = sc * dy;
                    accx -= px; accy -= py;
                    atomicAdd(&out[2 * j], px);
                    atomicAdd(&out[2 * j + 1], py);
                }
            }
        }
#pragma unroll
        for (int off = 32; off > 0; off >>= 1) {
            accx += __shfl_down(accx, off);
            accy += __shfl_down(accy, off);
        }
        if (lane == 0 && (accx != 0.f || accy != 0.f)) {
            atomicAdd(&out[2 * i], accx);
            atomicAdd(&out[2 * i + 1], accy);
        }
    }
}

__global__ void resolve_kernel(const float2* __restrict__ centers,
                               const float* __restrict__ radii,
                               const int* __restrict__ ccount,
                               const float4* __restrict__ cells,
                               const int* __restrict__ status,
                               float* __restrict__ out) {
    const int t = blockIdx.x * blockDim.x + threadIdx.x;
    if (t >= 3 * NB) return;
    const int i = t & (NB - 1);
    if (status[i] == 0) return;
    const int seg = t >> 13;
    const float2 ci = centers[i];
    const float ri = radii[i];
    const int cx = cell_of(ci.x), cy = cell_of(ci.y);
    const int yy = cy - 1 + seg;
    if (yy < 0 || yy >= GRID_DIM) return;
    const int x0 = max(cx - 1, 0), x1 = min(cx + 1, GRID_DIM - 1);
    float accx = 0.f, accy = 0.f;
    for (int xx = x0; xx <= x1; ++xx) {
        const int c = yy * GRID_DIM + xx;
        const int n = min(ccount[c], CAP);
        const float4* p = cells + c * CAP;
        for (int k = 0; k < n; ++k) {
            const float4 o = p[k];
            const int j = __float_as_int(o.w);
            if (j <= i) continue;
            const float rs = ri + o.z;
            const float dx = o.x - ci.x, dy = o.y - ci.y;
            if (!(fabsf(dx) <= rs && fabsf(dy) <= rs)) continue;
            const float dist = sqrtf(dx * dx + dy * dy + EPS);
            const float depth = rs - dist;
            if (depth <= 0.f) continue;
            const float sc = 0.5f * depth / dist;
            const float px = sc * dx, py = sc * dy;
            accx -= px; accy -= py;
            atomicAdd(&out[2 * j], px);
            atomicAdd(&out[2 * j + 1], py);
        }
    }
    if (accx != 0.f || accy != 0.f) {
        atomicAdd(&out[2 * i], accx);
        atomicAdd(&out[2 * i + 1], accy);
    }
}

extern "C" void kernel_launch(void* const* d_in, const int* in_sizes, int n_in,
                              void* d_out, int out_size, void* d_ws, size_t ws_size,
                              hipStream_t stream) {
    const float* centers = (const float*)d_in[0];
    const float* radii   = (const float*)d_in[1];
    const int* LBp = (const int*)d_in[2];
    const int* LNp = (const int*)d_in[3];
    float* out = (float*)d_out;

    int* ws = (int*)d_ws;
    int* ccount = ws + O_CCOUNT;
    int* rcomb  = ws + O_RCOMB;
    int* status = ws + O_STATUS;
    float4* cells = (float4*)(ws + O_CELLS);

    const float2* c2 = (const float2*)centers;

    hipMemsetAsync(ccount, 0, NCELLS * sizeof(int), stream);
    fill_kernel<<<NB / 256, 256, 0, stream>>>(c2, radii, ccount, cells, rcomb,
                                              (float2*)out);
    count_kernel<<<3 * NB / 256, 256, 0, stream>>>(c2, radii, ccount, cells, rcomb);
    scan_kernel<<<1, 1024, 0, stream>>>(c2, radii, ccount, cells, rcomb,
                                        LBp, LNp, status, out);
    resolve_kernel<<<3 * NB / 256, 256, 0, stream>>>(c2, radii, ccount, cells,
                                                     status, out);
}